// Round 8
// baseline (128.499 us; speedup 1.0000x reference)
//
#include <hip/hip_runtime.h>
#include <hip/hip_bf16.h>
#include <stdint.h>

#define BB 4
#define NN 2048
#define FF 128

typedef __attribute__((ext_vector_type(8))) short bf16x8;
typedef __attribute__((ext_vector_type(4))) float f32x4;

__device__ inline unsigned pk_bf16(float a, float b) {
    union { float f; unsigned u; } x, y;
    x.f = a; y.f = b;
    unsigned xu = x.u + (0x7fffu + ((x.u >> 16) & 1u));
    unsigned yu = y.u + (0x7fffu + ((y.u >> 16) & 1u));
    return (xu >> 16) | (yu & 0xffff0000u);
}

#define XT_P 136
#define WT_P 136

// ---------------- Kernel 1: h = x@W via bf16 MFMA, s = h@a_w + a_b, Ht bf16 ---------
__global__ __launch_bounds__(256) void k1_proj(
    const float* __restrict__ x, const float* __restrict__ W,
    const float* __restrict__ a_w, const float* __restrict__ a_b,
    uint16_t* __restrict__ Ht, float* __restrict__ s_out)
{
    __shared__ uint16_t xt[16 * XT_P];
    __shared__ uint16_t Wt[128 * WT_P];
    __shared__ float sredw[4 * 16];

    const int t = threadIdx.x;
    const int w = t >> 6, l = t & 63;
    const int m16 = l & 15, q = l >> 4;
    const int b = blockIdx.x >> 7;
    const int n0 = (blockIdx.x & 127) << 4;

    const int c4 = (t & 31) * 4, kh = (t >> 5) * 16;
    float4 wr0[8], wr1[8];
    #pragma unroll
    for (int kk = 0; kk < 8; ++kk) {
        const int k = kh + 2 * kk;
        wr0[kk] = *(const float4*)(W + (size_t)k * 128 + c4);
        wr1[kk] = *(const float4*)(W + (size_t)(k + 1) * 128 + c4);
    }
    {
        const int row = t >> 4, c0 = (t & 15) * 8;
        const float* xr = x + ((size_t)(b * NN + n0 + row)) * FF + c0;
        const float4 v0 = *(const float4*)xr;
        const float4 v1 = *(const float4*)(xr + 4);
        unsigned* dst = (unsigned*)(xt + row * XT_P + c0);
        dst[0] = pk_bf16(v0.x, v0.y); dst[1] = pk_bf16(v0.z, v0.w);
        dst[2] = pk_bf16(v1.x, v1.y); dst[3] = pk_bf16(v1.z, v1.w);
    }
    #pragma unroll
    for (int kk = 0; kk < 8; ++kk) {
        const int k = kh + 2 * kk;
        *(unsigned*)(Wt + (c4 + 0) * WT_P + k) = pk_bf16(wr0[kk].x, wr1[kk].x);
        *(unsigned*)(Wt + (c4 + 1) * WT_P + k) = pk_bf16(wr0[kk].y, wr1[kk].y);
        *(unsigned*)(Wt + (c4 + 2) * WT_P + k) = pk_bf16(wr0[kk].z, wr1[kk].z);
        *(unsigned*)(Wt + (c4 + 3) * WT_P + k) = pk_bf16(wr0[kk].w, wr1[kk].w);
    }
    const int g0 = (2 * w) * 16 + m16, g1 = (2 * w + 1) * 16 + m16;
    const float aw0 = a_w[g0], aw1 = a_w[g1];
    __syncthreads();

    f32x4 acc0 = {}, acc1 = {};
    bf16x8 af[4];
    #pragma unroll
    for (int dk = 0; dk < 4; ++dk)
        af[dk] = *(const bf16x8*)(xt + m16 * XT_P + dk * 32 + q * 8);
    #pragma unroll
    for (int dk = 0; dk < 4; ++dk) {
        bf16x8 b0 = *(const bf16x8*)(Wt + g0 * WT_P + dk * 32 + q * 8);
        bf16x8 b1 = *(const bf16x8*)(Wt + g1 * WT_P + dk * 32 + q * 8);
        acc0 = __builtin_amdgcn_mfma_f32_16x16x32_bf16(af[dk], b0, acc0, 0, 0, 0);
        acc1 = __builtin_amdgcn_mfma_f32_16x16x32_bf16(af[dk], b1, acc1, 0, 0, 0);
    }

    float sp[4];
    #pragma unroll
    for (int r = 0; r < 4; ++r) sp[r] = acc0[r] * aw0 + acc1[r] * aw1;
    #pragma unroll
    for (int off = 1; off < 16; off <<= 1)
        #pragma unroll
        for (int r = 0; r < 4; ++r) sp[r] += __shfl_xor(sp[r], off, 64);
    if (m16 == 0) {
        #pragma unroll
        for (int r = 0; r < 4; ++r) sredw[w * 16 + q * 4 + r] = sp[r];
    }
    {
        uint2 o0 = { pk_bf16(acc0[0], acc0[1]), pk_bf16(acc0[2], acc0[3]) };
        uint2 o1 = { pk_bf16(acc1[0], acc1[1]), pk_bf16(acc1[2], acc1[3]) };
        *(uint2*)(Ht + ((size_t)(b * 128 + g0)) * NN + n0 + q * 4) = o0;
        *(uint2*)(Ht + ((size_t)(b * 128 + g1)) * NN + n0 + q * 4) = o1;
    }
    __syncthreads();
    if (t < 16)
        s_out[b * NN + n0 + t] = sredw[t] + sredw[16 + t] + sredw[32 + t] + sredw[48 + t] + a_b[0];
}

// ---------------- Kernel 2: register-resident split-K attention, split-g waves -------
// Grid: js(8) x is(16) x b(4) = 512 blocks, 512 thr (8 waves). Wave (jh,gh):
// 64 j x 64 g -> hf = 8 frags (32 VGPR), acc = 4 (16 VGPR); ~140 total ->
// 3 waves/SIMD, no spills. gh-pair waves re-read same A lines (L2-hot, HBM 1x).
// Barriers are lgkm-only; asm memory clobber pins the A-prefetch issue point.
#define JS 8
#define IRND 8

__global__ __launch_bounds__(512, 3) void k2_attn(
    const float* __restrict__ A, const uint16_t* __restrict__ Ht,
    const float* __restrict__ s, uint16_t* __restrict__ po,
    float* __restrict__ prs)
{
    __shared__ float Opw[8][16 * 68];   // 34.8 KB
    __shared__ float rsw[4][16];

    const int t = threadIdx.x;
    const int w = t >> 6, l = t & 63;
    const int m16 = l & 15, q = l >> 4;
    const int gh = w & 1, jh = w >> 1;

    const int bx = blockIdx.x;
    const int js = bx & 7;
    const int is = (bx >> 3) & 15;
    const int b  = bx >> 7;
    const int j0 = js * 256;
    const int ibase = is * 128;

    const float* sb = s + b * NN;
    const float* Ab = A + (size_t)b * NN * NN;
    const uint16_t* Hb = Ht + (size_t)b * FF * NN;

    const int jcb = j0 + jh * 64;
    const int jq0 = jcb + q * 8;
    const int jq1 = jcb + 32 + q * 8;

    // loop-invariant sj (16 per lane)
    float4 sj0 = *(const float4*)(sb + jq0);
    float4 sj1 = *(const float4*)(sb + jq0 + 4);
    float4 sj2 = *(const float4*)(sb + jq1);
    float4 sj3 = *(const float4*)(sb + jq1 + 4);

    // h-frags: 4 gt x 2 kt (32 VGPR)
    bf16x8 hf[4][2];
    #pragma unroll
    for (int gt = 0; gt < 4; ++gt) {
        const uint16_t* hp = Hb + (size_t)(gh * 64 + gt * 16 + m16) * NN;
        hf[gt][0] = *(const bf16x8*)(hp + jq0);
        hf[gt][1] = *(const bf16x8*)(hp + jq1);
    }

    // round-0 A prefetch
    const float* Ar = Ab + (size_t)(ibase + m16) * NN;
    float4 a0 = *(const float4*)(Ar + jq0);
    float4 a1 = *(const float4*)(Ar + jq0 + 4);
    float4 a2 = *(const float4*)(Ar + jq1);
    float4 a3 = *(const float4*)(Ar + jq1 + 4);
    float si = sb[ibase + m16];

    const size_t slice = (size_t)(js * BB + b);

    for (int r = 0; r < IRND; ++r) {
        const int i0r = ibase + r * 16;
        const int i0n = ibase + ((r + 1) & (IRND - 1)) * 16;

        // prefetch next round (pinned before barrier-1 by asm memory clobber)
        const float* An = Ab + (size_t)(i0n + m16) * NN;
        float4 n0 = *(const float4*)(An + jq0);
        float4 n1 = *(const float4*)(An + jq0 + 4);
        float4 n2 = *(const float4*)(An + jq1);
        float4 n3 = *(const float4*)(An + jq1 + 4);
        const float sin_ = sb[i0n + m16];

        const float svv[16] = {sj0.x,sj0.y,sj0.z,sj0.w, sj1.x,sj1.y,sj1.z,sj1.w,
                               sj2.x,sj2.y,sj2.z,sj2.w, sj3.x,sj3.y,sj3.z,sj3.w};
        const float avv[16] = {a0.x,a0.y,a0.z,a0.w, a1.x,a1.y,a1.z,a1.w,
                               a2.x,a2.y,a2.z,a2.w, a3.x,a3.y,a3.z,a3.w};
        float pv[16]; float rs = 0.f;
        #pragma unroll
        for (int j = 0; j < 16; ++j) {
            float e = si + svv[j];
            e = fmaxf(e, 0.2f * e);               // LeakyReLU(0.2)
            pv[j] = __expf(e + avv[j]);
            rs += pv[j];
        }
        union { unsigned u[4]; bf16x8 v; } fa0, fa1;
        #pragma unroll
        for (int j = 0; j < 4; ++j) {
            fa0.u[j] = pk_bf16(pv[2 * j], pv[2 * j + 1]);
            fa1.u[j] = pk_bf16(pv[8 + 2 * j], pv[9 + 2 * j]);
        }

        // 8 MFMAs: wave's P(16x64) x its 64 g
        f32x4 acc[4];
        #pragma unroll
        for (int gt = 0; gt < 4; ++gt) {
            f32x4 z = {0.f, 0.f, 0.f, 0.f};
            z = __builtin_amdgcn_mfma_f32_16x16x32_bf16(fa0.v, hf[gt][0], z, 0, 0, 0);
            acc[gt] = __builtin_amdgcn_mfma_f32_16x16x32_bf16(fa1.v, hf[gt][1], z, 0, 0, 0);
        }

        // row-sum partials over this wave's 64 j (gh=1 duplicates; skip its store)
        rs += __shfl_xor(rs, 16, 64);
        rs += __shfl_xor(rs, 32, 64);
        if (gh == 0 && q == 0) rsw[jh][m16] = rs;

        // stage O partial (C-layout: row=q*4+rr, col=gt*16+m16 within g-half)
        #pragma unroll
        for (int gt = 0; gt < 4; ++gt)
            #pragma unroll
            for (int rr = 0; rr < 4; ++rr)
                Opw[w][(q * 4 + rr) * 68 + gt * 16 + m16] = acc[gt][rr];
        asm volatile("s_waitcnt lgkmcnt(0)\n\ts_barrier" ::: "memory");

        // cross-jh reduce + store (unnormalized; k3 divides)
        {
            const int row = t >> 5;           // 0..15
            const int c4 = (t & 31) * 4;      // 0..124
            const int gh2 = c4 >> 6;
            const int cc = c4 & 63;
            float4 v = {0.f, 0.f, 0.f, 0.f};
            #pragma unroll
            for (int jh2 = 0; jh2 < 4; ++jh2) {
                float4 u = *(const float4*)&Opw[jh2 * 2 + gh2][row * 68 + cc];
                v.x += u.x; v.y += u.y; v.z += u.z; v.w += u.w;
            }
            unsigned* op = (unsigned*)(po + ((slice * NN + i0r + row) * FF + c4));
            op[0] = pk_bf16(v.x, v.y);
            op[1] = pk_bf16(v.z, v.w);
            if (t < 16)
                prs[slice * NN + i0r + t] = rsw[0][t] + rsw[1][t] + rsw[2][t] + rsw[3][t];
        }
        asm volatile("s_waitcnt lgkmcnt(0)\n\ts_barrier" ::: "memory");

        a0 = n0; a1 = n1; a2 = n2; a3 = n3; si = sin_;
    }
}

// ---------------- Kernel 3: reduce 8 partials, normalize, bias (vectorized) ---------
__global__ __launch_bounds__(256) void k3_red(
    const uint16_t* __restrict__ po, const float* __restrict__ prs,
    const float* __restrict__ bias, float* __restrict__ out)
{
    const int idx = blockIdx.x * 256 + threadIdx.x;   // (b, i, g-quad)
    const int g4 = (idx & 31) * 4;
    const int i = (idx >> 5) & (NN - 1);
    const int b = idx >> 16;

    float v0 = 0.f, v1 = 0.f, v2 = 0.f, v3 = 0.f, rsum = 0.f;
    #pragma unroll
    for (int js = 0; js < JS; ++js) {
        const size_t base = (size_t)(js * BB + b) * NN + i;
        uint2 u = *(const uint2*)(po + base * FF + g4);
        union { unsigned u; float f; } c0, c1, c2, c3;
        c0.u = u.x << 16; c1.u = u.x & 0xffff0000u;
        c2.u = u.y << 16; c3.u = u.y & 0xffff0000u;
        v0 += c0.f; v1 += c1.f; v2 += c2.f; v3 += c3.f;
        rsum += prs[base];
    }
    const float inv = 1.0f / rsum;
    float4 bv = *(const float4*)(bias + g4);
    float4 o = { v0 * inv + bv.x, v1 * inv + bv.y, v2 * inv + bv.z, v3 * inv + bv.w };
    *(float4*)(out + ((size_t)b * NN + i) * FF + g4) = o;
}

extern "C" void kernel_launch(void* const* d_in, const int* in_sizes, int n_in,
                              void* d_out, int out_size, void* d_ws, size_t ws_size,
                              hipStream_t stream) {
    const float* x    = (const float*)d_in[0];
    const float* A    = (const float*)d_in[1];
    const float* W    = (const float*)d_in[2];
    const float* a_w  = (const float*)d_in[3];
    const float* a_b  = (const float*)d_in[4];
    const float* bias = (const float*)d_in[5];
    float* out = (float*)d_out;

    char* ws = (char*)d_ws;
    uint16_t* Ht = (uint16_t*)ws;                                  // 2 MB
    float* s = (float*)(ws + 2 * 1024 * 1024);                     // 32 KB (pad to 64K)
    uint16_t* po = (uint16_t*)(ws + 2 * 1024 * 1024 + 65536);      // 16.8 MB
    float* prs = (float*)(ws + 2 * 1024 * 1024 + 65536 + (size_t)JS * BB * NN * FF * 2);  // 256 KB

    k1_proj<<<BB * (NN / 16), 256, 0, stream>>>(x, W, a_w, a_b, Ht, s);
    k2_attn<<<JS * 16 * BB, 512, 0, stream>>>(A, Ht, s, po, prs);
    k3_red<<<(BB * NN * 32) / 256, 256, 0, stream>>>(po, prs, bias, out);
}